// Round 12
// baseline (7588.488 us; speedup 1.0000x reference)
//
#include <hip/hip_runtime.h>
#include <hip/hip_bf16.h>

#define BATCH 4
#define TLEN 16384
#define CH 128
#define HC 64
#define TPRIME 10246
#define LDIFF 3069
#define NLAYERS 30
#define FC1C 2048
#define FC2C 256
#define ZK 1920              // 30 layers * 64 z-channels
#define NBLK 512             // grid of the fused layer kernel (2 blocks/CU needed)

typedef short bf16x8 __attribute__((ext_vector_type(8)));
typedef float f32x4 __attribute__((ext_vector_type(4)));
#define MFMA(a, b, c) __builtin_amdgcn_mfma_f32_16x16x32_bf16(a, b, c, 0, 0, 0)

static __device__ __forceinline__ short f2b(float f) {
    __hip_bfloat16 h = __float2bfloat16(f);
    return *reinterpret_cast<short*>(&h);
}
static __device__ __forceinline__ float b2f(short s) {
    __hip_bfloat16 h;
    *reinterpret_cast<short*>(&h) = s;
    return __bfloat162float(h);
}

// ---------------------------------------------------------------- MFMA weight packer (PROVEN r3-r10)
// out layout: [cob][tap][kc][kg(4)][co(128)][j(8)]  (bf16), ci = kc*32+kg*8+j
__global__ void k_prep_conv(const float* __restrict__ W, short* __restrict__ Wp,
                            int CIN, int KC, int total) {
    int o = blockIdx.x * 256 + threadIdx.x;
    if (o >= total) return;
    int j = o & 7;
    int co = (o >> 3) & 127;
    int kg = (o >> 10) & 3;
    int rest = o >> 12;       // = (cob*3+tap)*KC + kc
    int kc = rest % KC;
    int ct = rest / KC;
    int tap = ct % 3;
    int cob = ct / 3;
    int ci = kc * 32 + kg * 8 + j;
    int cog = cob * 128 + co;
    Wp[o] = f2b(W[((size_t)cog * CIN + ci) * 3 + tap]);
}

// skip/res 1x1 weights: out [layer][kg(8)][co(128)][j(8)], cz = kg*8+j (PROVEN r4-r10)
__global__ void k_prep_sr(const float* __restrict__ Ws, const float* __restrict__ Wr,
                          short* __restrict__ Wsp, short* __restrict__ Wrp) {
    int o = blockIdx.x * 256 + threadIdx.x;
    if (o >= NLAYERS * 8192) return;
    int j = o & 7;
    int co = (o >> 3) & 127;
    int kg = (o >> 10) & 7;
    int lay = o >> 13;
    size_t in = ((size_t)lay * 128 + co) * 64 + kg * 8 + j;
    Wsp[o] = f2b(Ws[in]);
    Wrp[o] = f2b(Wr[in]);
}

// ---------------------------------------------------------------- first conv -> h[b][t][c] bf16 (PROVEN r4)
__global__ __launch_bounds__(256) void k_first(const float* __restrict__ x,
                                               const float* __restrict__ Wf,
                                               short* __restrict__ h) {
    int gid = blockIdx.x * 256 + threadIdx.x;   // B*T*32 units of 4 co
    int co4 = (gid & 31) * 4;
    int t = (gid >> 5) & (TLEN - 1);
    int b = gid >> 19;
    const float* xb = x + (size_t)b * TLEN;
    float xm = t > 0 ? xb[t - 1] : 0.f;
    float x0 = xb[t];
    float xp = t < TLEN - 1 ? xb[t + 1] : 0.f;
    short4 o;
    float r[4];
#pragma unroll
    for (int i = 0; i < 4; ++i) {
        const float* wp = Wf + (co4 + i) * 3;
        r[i] = wp[0] * xm + wp[1] * x0 + wp[2] * xp;
    }
    o.x = f2b(r[0]); o.y = f2b(r[1]); o.z = f2b(r[2]); o.w = f2b(r[3]);
    *(short4*)(h + (size_t)b * TLEN * CH + (size_t)t * CH + co4) = o;
}

// ---------------------------------------------------------------- ALL 30 layers, one launch
// Body per layer/tile = v10 k_layer (PROVEN r10). Hand-rolled grid barrier
// between layers (plain launch; cooperative API unsupported by harness).
// Residency arithmetic: 512 blocks, LDS 25.6KB (6/CU), launch_bounds(256,4)
// caps VGPR<=128 (measured 60) -> capacity >= 4/CU = 1024 >= 512. One fresh
// counter per layer, memset to 0 on-stream each call (graph-replay safe).
__global__ __launch_bounds__(256, 4) void k_layers_all(
    short* __restrict__ hA, short* __restrict__ hB,
    short* __restrict__ zbuf,
    const short* __restrict__ WpD,          // [30][3][4][4][128][8]
    const short* __restrict__ WrpA,         // [30][8][128][8]
    unsigned* __restrict__ bar) {           // [NLAYERS] zeroed counters
    __shared__ __align__(16) short SZ[4096];      // z: [kg8][tt64][j8] = 8 KB
    __shared__ __align__(16) short HT[8704];      // h tile [tt64][136] = 17 KB
    const int tid = threadIdx.x;
    const int l = tid & 63;
    const int w = tid >> 6;
    const int lm = l & 15;
    const int quad = l >> 4;
    const int b = blockIdx.y;
    const int tq = w * 16;
    int4* HT4 = (int4*)HT;

    for (int lyr = 0; lyr < NLAYERS; ++lyr) {
        const short* hin = (lyr & 1) ? hB : hA;
        short* hout = (lyr & 1) ? hA : hB;
        const int d = 1 << (lyr % 10);
        const bf16x8* Wg = (const bf16x8*)(WpD + (size_t)lyr * 49152);
        const bf16x8* Wrg = (const bf16x8*)(WrpA + (size_t)lyr * 8192);
        const short* hb = hin + (size_t)b * TLEN * CH;
        const bool last = (lyr == NLAYERS - 1);

        for (int half = 0; half < 2; ++half) {
            const int t0 = (blockIdx.x + half * 128) * 64;
            if (half == 1) __syncthreads();   // protect SZ/HT reuse across halves

            f32x4 acc[8] = {};
            for (int tap = 0; tap < 3; ++tap) {
                const int toff = (tap - 1) * d;
#pragma unroll
                for (int kc = 0; kc < 4; ++kc) {
                    bf16x8 af[8], bfr;
#pragma unroll
                    for (int i = 0; i < 8; ++i)
                        af[i] = Wg[(tap * 4 + kc) * 512 + quad * 128 + i * 16 + lm];
                    {
                        int tg = t0 + tq + lm + toff;
                        bf16x8 v = {};
                        if ((unsigned)tg < TLEN)
                            v = *(const bf16x8*)(hb + (size_t)tg * CH + kc * 32 + quad * 8);
                        bfr = v;
                    }
#pragma unroll
                    for (int i = 0; i < 8; ++i)
                        acc[i] = MFMA(af[i], bfr, acc[i]);
                }
            }

            // ---- stage h_in tile coalesced (skipped on last layer: h_out dead)
            if (!last) {
                for (int u = tid; u < 1024; u += 256) {
                    int tt = u >> 4, kg = u & 15;
                    HT4[tt * 17 + kg] = *(const int4*)(hb + (size_t)(t0 + tt) * CH + kg * 8);
                }
            }

            // ---- GLU in-register, z -> SZ in B-operand layout (PROVEN r4-r10)
#pragma unroll
            for (int i = 0; i < 4; ++i) {
                short zo[4];
#pragma unroll
                for (int r = 0; r < 4; ++r) {
                    float a = acc[i][r];          // co = i*16+quad*4+r  (filter)
                    float g = acc[i + 4][r];      // co + 64             (gate)
                    float th = tanhf(a);
                    float sg = 1.f / (1.f + __expf(-g));
                    zo[r] = f2b(th * sg);
                }
                int co = i * 16 + quad * 4;       // cz in [0,64)
                int kg = co >> 3;
                int jj0 = co & 7;                 // 0 or 4
                short4 zv = {zo[0], zo[1], zo[2], zo[3]};
                *(short4*)(SZ + (kg * 64 + tq + lm) * 8 + jj0) = zv;
            }
            __syncthreads();                       // covers SZ writes AND HT staging

            if (!last) {
                // ---- res GEMM, K=64; weights direct from global (PROVEN r5-r10)
                f32x4 aR[8] = {};
#pragma unroll
                for (int kk = 0; kk < 2; ++kk) {
                    int kgg = kk * 4 + quad;
                    bf16x8 zs, wrf[8];
                    zs = *(const bf16x8*)(SZ + (kgg * 64 + tq + lm) * 8);
#pragma unroll
                    for (int i = 0; i < 8; ++i)
                        wrf[i] = Wrg[kgg * 128 + i * 16 + lm];
#pragma unroll
                    for (int i = 0; i < 8; ++i)
                        aR[i] = MFMA(wrf[i], zs, aR[i]);
                }

                // ---- residual RMW in LDS (each lane owns its address)
                const float scale = 0.70710678118654752f;
                {
                    int tt = tq + lm;
#pragma unroll
                    for (int i = 0; i < 8; ++i) {
                        int co = i * 16 + quad * 4;
                        short4 hv = *(const short4*)(HT + tt * 136 + co);
                        short4 ho;
                        ho.x = f2b((b2f(hv.x) + aR[i][0]) * scale);
                        ho.y = f2b((b2f(hv.y) + aR[i][1]) * scale);
                        ho.z = f2b((b2f(hv.z) + aR[i][2]) * scale);
                        ho.w = f2b((b2f(hv.w) + aR[i][3]) * scale);
                        *(short4*)(HT + tt * 136 + co) = ho;
                    }
                }
                __syncthreads();

                // ---- coalesced h_out copy
                short* hob = hout + (size_t)b * TLEN * CH;
                for (int u = tid; u < 1024; u += 256) {
                    int tt = u >> 4, kg = u & 15;
                    *(int4*)(hob + (size_t)(t0 + tt) * CH + kg * 8) = HT4[tt * 17 + kg];
                }
            }

            // ---- z write (only t' in range)
            short* zb = zbuf + (size_t)lyr * 64 + (size_t)b * TPRIME * ZK;
            for (int u = tid; u < 512; u += 256) {
                int tt = u >> 3, kg = u & 7;
                int ts = t0 + tt - LDIFF;
                if ((unsigned)ts < TPRIME)
                    *(int4*)(zb + (size_t)ts * ZK + kg * 8) = *(const int4*)(SZ + (kg * 64 + tt) * 8);
            }
        }

        if (!last) {
            // ---- hand-rolled grid barrier (one fresh counter per layer)
            __syncthreads();
            __threadfence();                          // release: drain to device scope
            if (tid == 0) {
                atomicAdd(&bar[lyr], 1u);
                unsigned it = 0;
                while (atomicAdd(&bar[lyr], 0u) < (unsigned)NBLK &&
                       ++it < (1u << 26))
                    __builtin_amdgcn_s_sleep(2);
            }
            __syncthreads();
            __threadfence();                          // acquire: invalidate stale caches
        }
    }
}

// ---------------------------------------------------------------- fused skip GEMM + relu -> sbf (PROVEN r9/r10)
__global__ __launch_bounds__(256) void k_skipgemm(
    const short* __restrict__ zbuf,   // [b][t'][1920]
    const short* __restrict__ Wsp,    // [kg240][co128][j8]
    short* __restrict__ sbf) {        // [b][t'][128]
    const int tid = threadIdx.x;
    const int l = tid & 63;
    const int w = tid >> 6;
    const int lm = l & 15;
    const int quad = l >> 4;
    const int b = blockIdx.y;
    const int t0 = blockIdx.x * 64;
    const int coq = (w & 1) * 64;
    const int tq = (w >> 1) * 32;
    const short* zb = zbuf + (size_t)b * TPRIME * ZK;
    const bf16x8* Wsg = (const bf16x8*)Wsp;

    f32x4 acc[4][2] = {};
    for (int kc = 0; kc < 60; ++kc) {
        bf16x8 af[4], bfr[2];
#pragma unroll
        for (int i = 0; i < 4; ++i)
            af[i] = Wsg[(kc * 4 + quad) * 128 + coq + i * 16 + lm];
#pragma unroll
        for (int j = 0; j < 2; ++j) {
            int tg = t0 + tq + j * 16 + lm;
            bf16x8 v = {};
            if (tg < TPRIME)
                v = *(const bf16x8*)(zb + (size_t)tg * ZK + kc * 32 + quad * 8);
            bfr[j] = v;
        }
#pragma unroll
        for (int i = 0; i < 4; ++i)
#pragma unroll
            for (int j = 0; j < 2; ++j)
                acc[i][j] = MFMA(af[i], bfr[j], acc[i][j]);
    }
    short* sb = sbf + (size_t)b * TPRIME * CH;
#pragma unroll
    for (int i = 0; i < 4; ++i)
#pragma unroll
        for (int j = 0; j < 2; ++j) {
            int tg = t0 + tq + j * 16 + lm;
            int co = coq + i * 16 + quad * 4;
            if (tg < TPRIME) {
                short4 v;
                v.x = f2b(fmaxf(acc[i][j][0], 0.f));
                v.y = f2b(fmaxf(acc[i][j][1], 0.f));
                v.z = f2b(fmaxf(acc[i][j][2], 0.f));
                v.w = f2b(fmaxf(acc[i][j][3], 0.f));
                *(short4*)(sb + (size_t)tg * CH + co) = v;
            }
        }
}

// ---------------------------------------------------------------- fused head (PROVEN r10, K-split x8)
__global__ __launch_bounds__(256) void k_head(
    const short* __restrict__ sbf,
    const short* __restrict__ Wp1,   // [16][3][4][4][128][8]
    const short* __restrict__ Wp2,   // [2][3][64][4][128][8]
    const float* __restrict__ Wlast,
    float* __restrict__ out) {
    __shared__ __align__(16) char smem[36448];   // SB1 18496 + Y 17952
    int4*  SB1 = (int4*)smem;                    // [68 rows][17 int4]
    short* Y   = (short*)(smem + 18496);         // [66 rows][136 shorts]
    __shared__ float red[64];
    const int tid = threadIdx.x;
    const int l = tid & 63;
    const int w = tid >> 6;
    const int lm = l & 15;
    const int quad = l >> 4;
    const int ks = blockIdx.y;                   // 8 splits x 2 cic
    const int b = blockIdx.z;
    const int t0 = blockIdx.x * 64;
    const short* sb = sbf + (size_t)b * TPRIME * CH;

    for (int u = tid; u < 1088; u += 256) {
        int tt = u >> 4, kg = u & 15;
        int tg = t0 - 2 + tt;
        int4 v = make_int4(0, 0, 0, 0);
        if ((unsigned)tg < TPRIME)
            v = *(const int4*)(sb + (size_t)tg * CH + kg * 8);
        SB1[tt * 17 + kg] = v;
    }
    if (tid < 64) red[tid] = 0.f;
    __syncthreads();

    const bf16x8* W1 = (const bf16x8*)Wp1;
    const bf16x8* W2 = (const bf16x8*)Wp2;
    const int cob2 = w >> 1;
    const int coq2 = (w & 1) * 64;
    f32x4 acc2[4][4] = {};

    for (int cic = ks * 2; cic < ks * 2 + 2; ++cic) {
        f32x4 acc1[2][5] = {};
#pragma unroll
        for (int tap = 0; tap < 3; ++tap)
#pragma unroll
            for (int kc = 0; kc < 4; ++kc) {
                bf16x8 a1[2], b1[5];
#pragma unroll
                for (int i = 0; i < 2; ++i)
                    a1[i] = W1[((size_t)(cic * 3 + tap) * 4 + kc) * 512 +
                               quad * 128 + 32 * w + i * 16 + lm];
#pragma unroll
                for (int j = 0; j < 5; ++j) {
                    int r = j * 16 + lm + tap;
                    b1[j] = *(const bf16x8*)(SB1 + r * 17 + kc * 4 + quad);
                }
#pragma unroll
                for (int i = 0; i < 2; ++i)
#pragma unroll
                    for (int j = 0; j < 5; ++j)
                        acc1[i][j] = MFMA(a1[i], b1[j], acc1[i][j]);
            }
        __syncthreads();
#pragma unroll
        for (int i = 0; i < 2; ++i)
#pragma unroll
            for (int j = 0; j < 5; ++j) {
                int row = j * 16 + lm;
                if (row < 66) {
                    int co = 32 * w + i * 16 + quad * 4;
                    const bool valid = (unsigned)(t0 - 1 + row) < TPRIME;  // zero-pad edges
                    short4 v;
                    v.x = valid ? f2b(fmaxf(acc1[i][j][0], 0.f)) : (short)0;
                    v.y = valid ? f2b(fmaxf(acc1[i][j][1], 0.f)) : (short)0;
                    v.z = valid ? f2b(fmaxf(acc1[i][j][2], 0.f)) : (short)0;
                    v.w = valid ? f2b(fmaxf(acc1[i][j][3], 0.f)) : (short)0;
                    *(short4*)(Y + row * 136 + co) = v;
                }
            }
        __syncthreads();
#pragma unroll
        for (int tap = 0; tap < 3; ++tap)
#pragma unroll
            for (int kc = 0; kc < 4; ++kc) {
                bf16x8 a2[4], b2[4];
#pragma unroll
                for (int i = 0; i < 4; ++i)
                    a2[i] = W2[((size_t)(cob2 * 3 + tap) * 64 + cic * 4 + kc) * 512 +
                               quad * 128 + coq2 + i * 16 + lm];
#pragma unroll
                for (int j = 0; j < 4; ++j) {
                    int row = j * 16 + lm + tap;
                    b2[j] = *(const bf16x8*)(Y + row * 136 + kc * 32 + quad * 8);
                }
#pragma unroll
                for (int i = 0; i < 4; ++i)
#pragma unroll
                    for (int j = 0; j < 4; ++j)
                        acc2[i][j] = MFMA(a2[i], b2[j], acc2[i][j]);
            }
    }

    float4 wv[4];
#pragma unroll
    for (int i = 0; i < 4; ++i)
        wv[i] = *(const float4*)(Wlast + cob2 * 128 + coq2 + i * 16 + quad * 4);
#pragma unroll
    for (int j = 0; j < 4; ++j) {
        float s = 0.f;
#pragma unroll
        for (int i = 0; i < 4; ++i)
            s += wv[i].x * acc2[i][j][0] + wv[i].y * acc2[i][j][1] +
                 wv[i].z * acc2[i][j][2] + wv[i].w * acc2[i][j][3];
        atomicAdd(&red[j * 16 + lm], s);
    }
    __syncthreads();
    if (tid < 64) {
        int tg = t0 + tid;
        if (tg < TPRIME) atomicAdd(&out[(size_t)b * TPRIME + tg], red[tid]);
    }
}

// ---------------------------------------------------------------- bias init (PROVEN r4)
__global__ void k_bias(float* __restrict__ out, const float* __restrict__ bl) {
    int i = blockIdx.x * 256 + threadIdx.x;
    if (i < BATCH * TPRIME) out[i] = bl[0];
}

extern "C" void kernel_launch(void* const* d_in, const int* in_sizes, int n_in,
                              void* d_out, int out_size, void* d_ws, size_t ws_size,
                              hipStream_t stream) {
    const float* x = (const float*)d_in[0];
    const float* Wf = (const float*)d_in[1];
    const float* Wdil = (const float*)d_in[2];
    const float* Wskip = (const float*)d_in[3];
    const float* Wres = (const float*)d_in[4];
    const float* Wfc1 = (const float*)d_in[5];
    const float* Wfc2 = (const float*)d_in[6];
    const float* Wlast = (const float*)d_in[7];
    const float* blast = (const float*)d_in[8];
    float* out = (float*)d_out;

    char* p = (char*)d_ws;
    auto alloc = [&](size_t bytes) { char* r = p; p += (bytes + 255) & ~(size_t)255; return r; };
    short* zbuf  = (short*)alloc((size_t)BATCH * TPRIME * ZK * 2);   // 157.4 MB
    short* WpD   = (short*)alloc((size_t)NLAYERS * 49152 * 2);       // 2.95 MB
    short* Wsp   = (short*)alloc((size_t)NLAYERS * 8192 * 2);        // 0.49 MB (K-major image)
    short* Wrp   = (short*)alloc((size_t)NLAYERS * 8192 * 2);        // 0.49 MB
    short* Wp1   = (short*)alloc((size_t)786432 * 2);                // 1.5 MB
    short* Wp2   = (short*)alloc((size_t)1572864 * 2);               // 3.0 MB
    short* hA    = (short*)alloc((size_t)BATCH * TLEN * CH * 2);     // 16.78 MB
    short* hB    = (short*)alloc((size_t)BATCH * TLEN * CH * 2);     // 16.78 MB
    short* sbf   = (short*)alloc((size_t)BATCH * TPRIME * CH * 2);   // 10.49 MB
    unsigned* bar = (unsigned*)alloc(NLAYERS * sizeof(unsigned));    // grid-barrier counters
    // total ~210 MB

    hipMemsetAsync(bar, 0, NLAYERS * sizeof(unsigned), stream);
    k_prep_conv<<<5760, 256, 0, stream>>>(Wdil, WpD, 128, 4, 1474560);
    k_prep_conv<<<3072, 256, 0, stream>>>(Wfc1, Wp1, 128, 4, 786432);
    k_prep_conv<<<6144, 256, 0, stream>>>(Wfc2, Wp2, 2048, 64, 1572864);
    k_prep_sr<<<960, 256, 0, stream>>>(Wskip, Wres, Wsp, Wrp);
    k_first<<<8192, 256, 0, stream>>>(x, Wf, hA);

    // all 30 layers in ONE plain launch; hand-rolled grid barrier between layers
    k_layers_all<<<dim3(128, BATCH), 256, 0, stream>>>(hA, hB, zbuf, WpD, Wrp, bar);

    k_skipgemm<<<dim3(161, BATCH), 256, 0, stream>>>(zbuf, Wsp, sbf);
    k_bias<<<161, 256, 0, stream>>>(out, blast);
    k_head<<<dim3(161, 8, BATCH), 256, 0, stream>>>(sbf, Wp1, Wp2, Wlast, out);
}

// Round 13
// 4149.990 us; speedup vs baseline: 1.8286x; 1.8286x over previous
//
#include <hip/hip_runtime.h>
#include <hip/hip_bf16.h>

#define BATCH 4
#define TLEN 16384
#define CH 128
#define HC 64
#define TPRIME 10246
#define LDIFF 3069
#define NLAYERS 30
#define FC1C 2048
#define FC2C 256
#define ZK 1920              // 30 layers * 64 z-channels

typedef short bf16x8 __attribute__((ext_vector_type(8)));
typedef float f32x4 __attribute__((ext_vector_type(4)));
#define MFMA(a, b, c) __builtin_amdgcn_mfma_f32_16x16x32_bf16(a, b, c, 0, 0, 0)

static __device__ __forceinline__ short f2b(float f) {
    __hip_bfloat16 h = __float2bfloat16(f);
    return *reinterpret_cast<short*>(&h);
}
static __device__ __forceinline__ float b2f(short s) {
    __hip_bfloat16 h;
    *reinterpret_cast<short*>(&h) = s;
    return __bfloat162float(h);
}

// ---------------------------------------------------------------- MFMA weight packer (PROVEN r3-r10)
// out layout: [cob][tap][kc][kg(4)][co(128)][j(8)]  (bf16), ci = kc*32+kg*8+j
__global__ void k_prep_conv(const float* __restrict__ W, short* __restrict__ Wp,
                            int CIN, int KC, int total) {
    int o = blockIdx.x * 256 + threadIdx.x;
    if (o >= total) return;
    int j = o & 7;
    int co = (o >> 3) & 127;
    int kg = (o >> 10) & 3;
    int rest = o >> 12;       // = (cob*3+tap)*KC + kc
    int kc = rest % KC;
    int ct = rest / KC;
    int tap = ct % 3;
    int cob = ct / 3;
    int ci = kc * 32 + kg * 8 + j;
    int cog = cob * 128 + co;
    Wp[o] = f2b(W[((size_t)cog * CIN + ci) * 3 + tap]);
}

// skip/res 1x1 weights: out [layer][kg(8)][co(128)][j(8)], cz = kg*8+j (PROVEN r4-r10)
__global__ void k_prep_sr(const float* __restrict__ Ws, const float* __restrict__ Wr,
                          short* __restrict__ Wsp, short* __restrict__ Wrp) {
    int o = blockIdx.x * 256 + threadIdx.x;
    if (o >= NLAYERS * 8192) return;
    int j = o & 7;
    int co = (o >> 3) & 127;
    int kg = (o >> 10) & 7;
    int lay = o >> 13;
    size_t in = ((size_t)lay * 128 + co) * 64 + kg * 8 + j;
    Wsp[o] = f2b(Ws[in]);
    Wrp[o] = f2b(Wr[in]);
}

// ---------------------------------------------------------------- first conv -> h[b][t][c] bf16
// grid-strided (512 blocks) to cut WG-dispatch overhead vs r10's 8192 blocks
__global__ __launch_bounds__(256) void k_first(const float* __restrict__ x,
                                               const float* __restrict__ Wf,
                                               short* __restrict__ h) {
    for (int gid = blockIdx.x * 256 + threadIdx.x; gid < BATCH * TLEN * 32;
         gid += 512 * 256) {
        int co4 = (gid & 31) * 4;
        int t = (gid >> 5) & (TLEN - 1);
        int b = gid >> 19;
        const float* xb = x + (size_t)b * TLEN;
        float xm = t > 0 ? xb[t - 1] : 0.f;
        float x0 = xb[t];
        float xp = t < TLEN - 1 ? xb[t + 1] : 0.f;
        short4 o;
        float r[4];
#pragma unroll
        for (int i = 0; i < 4; ++i) {
            const float* wp = Wf + (co4 + i) * 3;
            r[i] = wp[0] * xm + wp[1] * x0 + wp[2] * xp;
        }
        o.x = f2b(r[0]); o.y = f2b(r[1]); o.z = f2b(r[2]); o.w = f2b(r[3]);
        *(short4*)(h + (size_t)b * TLEN * CH + (size_t)t * CH + co4) = o;
    }
}

// ---------------------------------------------------------------- layer kernel v13
// = r12's proven per-layer body (2 t-tiles per block via half-loop) as a plain
// per-layer dispatch: 512 WGs instead of r10's 1024 -> less dispatch ramp.
// Direct-global conv fragments, zero conv barriers, LDS-staged coalesced epilogue.
__global__ __launch_bounds__(256, 4) void k_layer(
    const short* __restrict__ hin, short* __restrict__ hout,
    short* __restrict__ zlay,               // zbuf + lyr*64
    const short* __restrict__ Wp,           // [3][4][4][128][8] this layer
    const short* __restrict__ Wrp,          // [8][128][8] this layer
    int d, int last) {
    __shared__ __align__(16) short SZ[4096];      // z: [kg8][tt64][j8] = 8 KB
    __shared__ __align__(16) short HT[8704];      // h tile [tt64][136] = 17 KB
    const int tid = threadIdx.x;
    const int l = tid & 63;
    const int w = tid >> 6;
    const int lm = l & 15;
    const int quad = l >> 4;
    const int b = blockIdx.y;
    const int tq = w * 16;
    int4* HT4 = (int4*)HT;
    const short* hb = hin + (size_t)b * TLEN * CH;
    const bf16x8* Wg = (const bf16x8*)Wp;
    const bf16x8* Wrg = (const bf16x8*)Wrp;

    for (int half = 0; half < 2; ++half) {
        const int t0 = (blockIdx.x + half * 128) * 64;
        if (half == 1) __syncthreads();   // protect SZ/HT reuse across halves

        f32x4 acc[8] = {};
        for (int tap = 0; tap < 3; ++tap) {
            const int toff = (tap - 1) * d;
#pragma unroll
            for (int kc = 0; kc < 4; ++kc) {
                bf16x8 af[8], bfr;
#pragma unroll
                for (int i = 0; i < 8; ++i)
                    af[i] = Wg[(tap * 4 + kc) * 512 + quad * 128 + i * 16 + lm];
                {
                    int tg = t0 + tq + lm + toff;
                    bf16x8 v = {};
                    if ((unsigned)tg < TLEN)
                        v = *(const bf16x8*)(hb + (size_t)tg * CH + kc * 32 + quad * 8);
                    bfr = v;
                }
#pragma unroll
                for (int i = 0; i < 8; ++i)
                    acc[i] = MFMA(af[i], bfr, acc[i]);
            }
        }

        // ---- stage h_in tile coalesced (skipped on last layer: h_out dead)
        if (!last) {
            for (int u = tid; u < 1024; u += 256) {
                int tt = u >> 4, kg = u & 15;
                HT4[tt * 17 + kg] = *(const int4*)(hb + (size_t)(t0 + tt) * CH + kg * 8);
            }
        }

        // ---- GLU in-register, z -> SZ in B-operand layout (PROVEN r4-r12)
#pragma unroll
        for (int i = 0; i < 4; ++i) {
            short zo[4];
#pragma unroll
            for (int r = 0; r < 4; ++r) {
                float a = acc[i][r];          // co = i*16+quad*4+r  (filter)
                float g = acc[i + 4][r];      // co + 64             (gate)
                float th = tanhf(a);
                float sg = 1.f / (1.f + __expf(-g));
                zo[r] = f2b(th * sg);
            }
            int co = i * 16 + quad * 4;       // cz in [0,64)
            int kg = co >> 3;
            int jj0 = co & 7;                 // 0 or 4
            short4 zv = {zo[0], zo[1], zo[2], zo[3]};
            *(short4*)(SZ + (kg * 64 + tq + lm) * 8 + jj0) = zv;
        }
        __syncthreads();                       // covers SZ writes AND HT staging

        if (!last) {
            // ---- res GEMM, K=64; weights direct from global (PROVEN r5-r12)
            f32x4 aR[8] = {};
#pragma unroll
            for (int kk = 0; kk < 2; ++kk) {
                int kgg = kk * 4 + quad;
                bf16x8 zs, wrf[8];
                zs = *(const bf16x8*)(SZ + (kgg * 64 + tq + lm) * 8);
#pragma unroll
                for (int i = 0; i < 8; ++i)
                    wrf[i] = Wrg[kgg * 128 + i * 16 + lm];
#pragma unroll
                for (int i = 0; i < 8; ++i)
                    aR[i] = MFMA(wrf[i], zs, aR[i]);
            }

            // ---- residual RMW in LDS (each lane owns its address)
            const float scale = 0.70710678118654752f;
            {
                int tt = tq + lm;
#pragma unroll
                for (int i = 0; i < 8; ++i) {
                    int co = i * 16 + quad * 4;
                    short4 hv = *(const short4*)(HT + tt * 136 + co);
                    short4 ho;
                    ho.x = f2b((b2f(hv.x) + aR[i][0]) * scale);
                    ho.y = f2b((b2f(hv.y) + aR[i][1]) * scale);
                    ho.z = f2b((b2f(hv.z) + aR[i][2]) * scale);
                    ho.w = f2b((b2f(hv.w) + aR[i][3]) * scale);
                    *(short4*)(HT + tt * 136 + co) = ho;
                }
            }
            __syncthreads();

            // ---- coalesced h_out copy
            short* hob = hout + (size_t)b * TLEN * CH;
            for (int u = tid; u < 1024; u += 256) {
                int tt = u >> 4, kg = u & 15;
                *(int4*)(hob + (size_t)(t0 + tt) * CH + kg * 8) = HT4[tt * 17 + kg];
            }
        }

        // ---- z write (only t' in range)
        short* zb = zlay + (size_t)b * TPRIME * ZK;
        for (int u = tid; u < 512; u += 256) {
            int tt = u >> 3, kg = u & 7;
            int ts = t0 + tt - LDIFF;
            if ((unsigned)ts < TPRIME)
                *(int4*)(zb + (size_t)ts * ZK + kg * 8) = *(const int4*)(SZ + (kg * 64 + tt) * 8);
        }
    }
}

// ---------------------------------------------------------------- fused skip GEMM + relu -> sbf (PROVEN r9-r12)
__global__ __launch_bounds__(256) void k_skipgemm(
    const short* __restrict__ zbuf,   // [b][t'][1920]
    const short* __restrict__ Wsp,    // [kg240][co128][j8]
    short* __restrict__ sbf) {        // [b][t'][128]
    const int tid = threadIdx.x;
    const int l = tid & 63;
    const int w = tid >> 6;
    const int lm = l & 15;
    const int quad = l >> 4;
    const int b = blockIdx.y;
    const int t0 = blockIdx.x * 64;
    const int coq = (w & 1) * 64;
    const int tq = (w >> 1) * 32;
    const short* zb = zbuf + (size_t)b * TPRIME * ZK;
    const bf16x8* Wsg = (const bf16x8*)Wsp;

    f32x4 acc[4][2] = {};
    for (int kc = 0; kc < 60; ++kc) {
        bf16x8 af[4], bfr[2];
#pragma unroll
        for (int i = 0; i < 4; ++i)
            af[i] = Wsg[(kc * 4 + quad) * 128 + coq + i * 16 + lm];
#pragma unroll
        for (int j = 0; j < 2; ++j) {
            int tg = t0 + tq + j * 16 + lm;
            bf16x8 v = {};
            if (tg < TPRIME)
                v = *(const bf16x8*)(zb + (size_t)tg * ZK + kc * 32 + quad * 8);
            bfr[j] = v;
        }
#pragma unroll
        for (int i = 0; i < 4; ++i)
#pragma unroll
            for (int j = 0; j < 2; ++j)
                acc[i][j] = MFMA(af[i], bfr[j], acc[i][j]);
    }
    short* sb = sbf + (size_t)b * TPRIME * CH;
#pragma unroll
    for (int i = 0; i < 4; ++i)
#pragma unroll
        for (int j = 0; j < 2; ++j) {
            int tg = t0 + tq + j * 16 + lm;
            int co = coq + i * 16 + quad * 4;
            if (tg < TPRIME) {
                short4 v;
                v.x = f2b(fmaxf(acc[i][j][0], 0.f));
                v.y = f2b(fmaxf(acc[i][j][1], 0.f));
                v.z = f2b(fmaxf(acc[i][j][2], 0.f));
                v.w = f2b(fmaxf(acc[i][j][3], 0.f));
                *(short4*)(sb + (size_t)tg * CH + co) = v;
            }
        }
}

// ---------------------------------------------------------------- fused head (PROVEN r10, K-split x8)
__global__ __launch_bounds__(256) void k_head(
    const short* __restrict__ sbf,
    const short* __restrict__ Wp1,   // [16][3][4][4][128][8]
    const short* __restrict__ Wp2,   // [2][3][64][4][128][8]
    const float* __restrict__ Wlast,
    float* __restrict__ out) {
    __shared__ __align__(16) char smem[36448];   // SB1 18496 + Y 17952
    int4*  SB1 = (int4*)smem;                    // [68 rows][17 int4]
    short* Y   = (short*)(smem + 18496);         // [66 rows][136 shorts]
    __shared__ float red[64];
    const int tid = threadIdx.x;
    const int l = tid & 63;
    const int w = tid >> 6;
    const int lm = l & 15;
    const int quad = l >> 4;
    const int ks = blockIdx.y;                   // 8 splits x 2 cic
    const int b = blockIdx.z;
    const int t0 = blockIdx.x * 64;
    const short* sb = sbf + (size_t)b * TPRIME * CH;

    for (int u = tid; u < 1088; u += 256) {
        int tt = u >> 4, kg = u & 15;
        int tg = t0 - 2 + tt;
        int4 v = make_int4(0, 0, 0, 0);
        if ((unsigned)tg < TPRIME)
            v = *(const int4*)(sb + (size_t)tg * CH + kg * 8);
        SB1[tt * 17 + kg] = v;
    }
    if (tid < 64) red[tid] = 0.f;
    __syncthreads();

    const bf16x8* W1 = (const bf16x8*)Wp1;
    const bf16x8* W2 = (const bf16x8*)Wp2;
    const int cob2 = w >> 1;
    const int coq2 = (w & 1) * 64;
    f32x4 acc2[4][4] = {};

    for (int cic = ks * 2; cic < ks * 2 + 2; ++cic) {
        f32x4 acc1[2][5] = {};
#pragma unroll
        for (int tap = 0; tap < 3; ++tap)
#pragma unroll
            for (int kc = 0; kc < 4; ++kc) {
                bf16x8 a1[2], b1[5];
#pragma unroll
                for (int i = 0; i < 2; ++i)
                    a1[i] = W1[((size_t)(cic * 3 + tap) * 4 + kc) * 512 +
                               quad * 128 + 32 * w + i * 16 + lm];
#pragma unroll
                for (int j = 0; j < 5; ++j) {
                    int r = j * 16 + lm + tap;
                    b1[j] = *(const bf16x8*)(SB1 + r * 17 + kc * 4 + quad);
                }
#pragma unroll
                for (int i = 0; i < 2; ++i)
#pragma unroll
                    for (int j = 0; j < 5; ++j)
                        acc1[i][j] = MFMA(a1[i], b1[j], acc1[i][j]);
            }
        __syncthreads();
#pragma unroll
        for (int i = 0; i < 2; ++i)
#pragma unroll
            for (int j = 0; j < 5; ++j) {
                int row = j * 16 + lm;
                if (row < 66) {
                    int co = 32 * w + i * 16 + quad * 4;
                    const bool valid = (unsigned)(t0 - 1 + row) < TPRIME;  // zero-pad edges
                    short4 v;
                    v.x = valid ? f2b(fmaxf(acc1[i][j][0], 0.f)) : (short)0;
                    v.y = valid ? f2b(fmaxf(acc1[i][j][1], 0.f)) : (short)0;
                    v.z = valid ? f2b(fmaxf(acc1[i][j][2], 0.f)) : (short)0;
                    v.w = valid ? f2b(fmaxf(acc1[i][j][3], 0.f)) : (short)0;
                    *(short4*)(Y + row * 136 + co) = v;
                }
            }
        __syncthreads();
#pragma unroll
        for (int tap = 0; tap < 3; ++tap)
#pragma unroll
            for (int kc = 0; kc < 4; ++kc) {
                bf16x8 a2[4], b2[4];
#pragma unroll
                for (int i = 0; i < 4; ++i)
                    a2[i] = W2[((size_t)(cob2 * 3 + tap) * 64 + cic * 4 + kc) * 512 +
                               quad * 128 + coq2 + i * 16 + lm];
#pragma unroll
                for (int j = 0; j < 4; ++j) {
                    int row = j * 16 + lm + tap;
                    b2[j] = *(const bf16x8*)(Y + row * 136 + kc * 32 + quad * 8);
                }
#pragma unroll
                for (int i = 0; i < 4; ++i)
#pragma unroll
                    for (int j = 0; j < 4; ++j)
                        acc2[i][j] = MFMA(a2[i], b2[j], acc2[i][j]);
            }
    }

    float4 wv[4];
#pragma unroll
    for (int i = 0; i < 4; ++i)
        wv[i] = *(const float4*)(Wlast + cob2 * 128 + coq2 + i * 16 + quad * 4);
#pragma unroll
    for (int j = 0; j < 4; ++j) {
        float s = 0.f;
#pragma unroll
        for (int i = 0; i < 4; ++i)
            s += wv[i].x * acc2[i][j][0] + wv[i].y * acc2[i][j][1] +
                 wv[i].z * acc2[i][j][2] + wv[i].w * acc2[i][j][3];
        atomicAdd(&red[j * 16 + lm], s);
    }
    __syncthreads();
    if (tid < 64) {
        int tg = t0 + tid;
        if (tg < TPRIME) atomicAdd(&out[(size_t)b * TPRIME + tg], red[tid]);
    }
}

// ---------------------------------------------------------------- bias init (PROVEN r4)
__global__ void k_bias(float* __restrict__ out, const float* __restrict__ bl) {
    int i = blockIdx.x * 256 + threadIdx.x;
    if (i < BATCH * TPRIME) out[i] = bl[0];
}

extern "C" void kernel_launch(void* const* d_in, const int* in_sizes, int n_in,
                              void* d_out, int out_size, void* d_ws, size_t ws_size,
                              hipStream_t stream) {
    const float* x = (const float*)d_in[0];
    const float* Wf = (const float*)d_in[1];
    const float* Wdil = (const float*)d_in[2];
    const float* Wskip = (const float*)d_in[3];
    const float* Wres = (const float*)d_in[4];
    const float* Wfc1 = (const float*)d_in[5];
    const float* Wfc2 = (const float*)d_in[6];
    const float* Wlast = (const float*)d_in[7];
    const float* blast = (const float*)d_in[8];
    float* out = (float*)d_out;

    char* p = (char*)d_ws;
    auto alloc = [&](size_t bytes) { char* r = p; p += (bytes + 255) & ~(size_t)255; return r; };
    short* zbuf  = (short*)alloc((size_t)BATCH * TPRIME * ZK * 2);   // 157.4 MB
    short* WpD   = (short*)alloc((size_t)NLAYERS * 49152 * 2);       // 2.95 MB
    short* Wsp   = (short*)alloc((size_t)NLAYERS * 8192 * 2);        // 0.49 MB (K-major image)
    short* Wrp   = (short*)alloc((size_t)NLAYERS * 8192 * 2);        // 0.49 MB
    short* Wp1   = (short*)alloc((size_t)786432 * 2);                // 1.5 MB
    short* Wp2   = (short*)alloc((size_t)1572864 * 2);               // 3.0 MB
    short* hA    = (short*)alloc((size_t)BATCH * TLEN * CH * 2);     // 16.78 MB
    short* hB    = (short*)alloc((size_t)BATCH * TLEN * CH * 2);     // 16.78 MB
    short* sbf   = (short*)alloc((size_t)BATCH * TPRIME * CH * 2);   // 10.49 MB
    // total ~210 MB

    k_prep_conv<<<5760, 256, 0, stream>>>(Wdil, WpD, 128, 4, 1474560);
    k_prep_conv<<<3072, 256, 0, stream>>>(Wfc1, Wp1, 128, 4, 786432);
    k_prep_conv<<<6144, 256, 0, stream>>>(Wfc2, Wp2, 2048, 64, 1572864);
    k_prep_sr<<<960, 256, 0, stream>>>(Wskip, Wres, Wsp, Wrp);
    k_first<<<512, 256, 0, stream>>>(x, Wf, hA);

    short* hin = hA;
    short* hout = hB;
    for (int lyr = 0; lyr < NLAYERS; ++lyr) {
        int d = 1 << (lyr % 10);
        k_layer<<<dim3(128, BATCH), 256, 0, stream>>>(
            hin, hout, zbuf + (size_t)lyr * 64,
            WpD + (size_t)lyr * 49152, Wrp + (size_t)lyr * 8192,
            d, lyr == NLAYERS - 1 ? 1 : 0);
        short* tmp = hin; hin = hout; hout = tmp;
    }

    k_skipgemm<<<dim3(161, BATCH), 256, 0, stream>>>(zbuf, Wsp, sbf);
    k_bias<<<161, 256, 0, stream>>>(out, blast);
    k_head<<<dim3(161, 8, BATCH), 256, 0, stream>>>(sbf, Wp1, Wp2, Wlast, out);
}

// Round 14
// 1178.396 us; speedup vs baseline: 6.4397x; 3.5217x over previous
//
#include <hip/hip_runtime.h>
#include <hip/hip_bf16.h>

#define BATCH 4
#define TLEN 16384
#define CH 128
#define HC 64
#define TPRIME 10246
#define LDIFF 3069
#define NLAYERS 30
#define FC1C 2048
#define FC2C 256
#define ZK 1920              // 30 layers * 64 z-channels

typedef short bf16x8 __attribute__((ext_vector_type(8)));
typedef float f32x4 __attribute__((ext_vector_type(4)));
#define MFMA(a, b, c) __builtin_amdgcn_mfma_f32_16x16x32_bf16(a, b, c, 0, 0, 0)

static __device__ __forceinline__ short f2b(float f) {
    __hip_bfloat16 h = __float2bfloat16(f);
    return *reinterpret_cast<short*>(&h);
}
static __device__ __forceinline__ float b2f(short s) {
    __hip_bfloat16 h;
    *reinterpret_cast<short*>(&h) = s;
    return __bfloat162float(h);
}

// ---------------------------------------------------------------- MFMA weight packer (PROVEN r3-r10)
// out layout: [cob][tap][kc][kg(4)][co(128)][j(8)]  (bf16), ci = kc*32+kg*8+j
__global__ void k_prep_conv(const float* __restrict__ W, short* __restrict__ Wp,
                            int CIN, int KC, int total) {
    int o = blockIdx.x * 256 + threadIdx.x;
    if (o >= total) return;
    int j = o & 7;
    int co = (o >> 3) & 127;
    int kg = (o >> 10) & 3;
    int rest = o >> 12;       // = (cob*3+tap)*KC + kc
    int kc = rest % KC;
    int ct = rest / KC;
    int tap = ct % 3;
    int cob = ct / 3;
    int ci = kc * 32 + kg * 8 + j;
    int cog = cob * 128 + co;
    Wp[o] = f2b(W[((size_t)cog * CIN + ci) * 3 + tap]);
}

// skip/res 1x1 weights: out [layer][kg(8)][co(128)][j(8)], cz = kg*8+j (PROVEN r4-r10)
__global__ void k_prep_sr(const float* __restrict__ Ws, const float* __restrict__ Wr,
                          short* __restrict__ Wsp, short* __restrict__ Wrp) {
    int o = blockIdx.x * 256 + threadIdx.x;
    if (o >= NLAYERS * 8192) return;
    int j = o & 7;
    int co = (o >> 3) & 127;
    int kg = (o >> 10) & 7;
    int lay = o >> 13;
    size_t in = ((size_t)lay * 128 + co) * 64 + kg * 8 + j;
    Wsp[o] = f2b(Ws[in]);
    Wrp[o] = f2b(Wr[in]);
}

// ---------------------------------------------------------------- first conv -> h[b][t][c] bf16 (PROVEN r4)
__global__ __launch_bounds__(256) void k_first(const float* __restrict__ x,
                                               const float* __restrict__ Wf,
                                               short* __restrict__ h) {
    int gid = blockIdx.x * 256 + threadIdx.x;   // B*T*32 units of 4 co
    int co4 = (gid & 31) * 4;
    int t = (gid >> 5) & (TLEN - 1);
    int b = gid >> 19;
    const float* xb = x + (size_t)b * TLEN;
    float xm = t > 0 ? xb[t - 1] : 0.f;
    float x0 = xb[t];
    float xp = t < TLEN - 1 ? xb[t + 1] : 0.f;
    short4 o;
    float r[4];
#pragma unroll
    for (int i = 0; i < 4; ++i) {
        const float* wp = Wf + (co4 + i) * 3;
        r[i] = wp[0] * xm + wp[1] * x0 + wp[2] * xp;
    }
    o.x = f2b(r[0]); o.y = f2b(r[1]); o.z = f2b(r[2]); o.w = f2b(r[3]);
    *(short4*)(h + (size_t)b * TLEN * CH + (size_t)t * CH + co4) = o;
}

// ---------------------------------------------------------------- layer kernel v10 (PROVEN r10)
// One contiguous 64-t tile per block (XCD-L2-locality-correct schedule).
// Direct-global conv fragments, zero conv barriers; h tile staged coalesced
// into HT; residual RMW in-place in LDS; coalesced copy-out. 2 barriers.
__global__ __launch_bounds__(256) void k_layer(
    const short* __restrict__ hin, short* __restrict__ hout,
    short* __restrict__ zlay,               // zbuf + lyr*64
    const short* __restrict__ Wp,           // [3][4][4][128][8] this layer
    const short* __restrict__ Wrp,          // [8][128][8] this layer
    int d) {
    __shared__ __align__(16) short SZ[4096];      // z: [kg8][tt64][j8] = 8 KB
    __shared__ __align__(16) short HT[8704];      // h tile [tt64][136] = 17 KB
    const int tid = threadIdx.x;
    const int l = tid & 63;
    const int w = tid >> 6;
    const int lm = l & 15;
    const int quad = l >> 4;
    const int b = blockIdx.y;
    const int t0 = blockIdx.x * 64;
    const int tq = w * 16;
    const short* hb = hin + (size_t)b * TLEN * CH;
    const bf16x8* Wg = (const bf16x8*)Wp;
    int4* HT4 = (int4*)HT;

    f32x4 acc[8] = {};
    for (int tap = 0; tap < 3; ++tap) {
        const int toff = (tap - 1) * d;
#pragma unroll
        for (int kc = 0; kc < 4; ++kc) {
            bf16x8 af[8], bfr;
#pragma unroll
            for (int i = 0; i < 8; ++i)
                af[i] = Wg[(tap * 4 + kc) * 512 + quad * 128 + i * 16 + lm];
            {
                int tg = t0 + tq + lm + toff;
                bf16x8 v = {};
                if ((unsigned)tg < TLEN)
                    v = *(const bf16x8*)(hb + (size_t)tg * CH + kc * 32 + quad * 8);
                bfr = v;
            }
#pragma unroll
            for (int i = 0; i < 8; ++i)
                acc[i] = MFMA(af[i], bfr, acc[i]);
        }
    }

    // ---- stage h_in tile coalesced (no barrier needed; HT disjoint from SZ)
    for (int u = tid; u < 1024; u += 256) {
        int tt = u >> 4, kg = u & 15;
        HT4[tt * 17 + kg] = *(const int4*)(hb + (size_t)(t0 + tt) * CH + kg * 8);
    }

    // ---- GLU in-register, z -> SZ in B-operand layout (PROVEN r4-r10)
#pragma unroll
    for (int i = 0; i < 4; ++i) {
        short zo[4];
#pragma unroll
        for (int r = 0; r < 4; ++r) {
            float a = acc[i][r];          // co = i*16+quad*4+r  (filter)
            float g = acc[i + 4][r];      // co + 64             (gate)
            float th = tanhf(a);
            float sg = 1.f / (1.f + __expf(-g));
            zo[r] = f2b(th * sg);
        }
        int co = i * 16 + quad * 4;       // cz in [0,64)
        int kg = co >> 3;
        int jj0 = co & 7;                 // 0 or 4
        short4 zv = {zo[0], zo[1], zo[2], zo[3]};
        *(short4*)(SZ + (kg * 64 + tq + lm) * 8 + jj0) = zv;
    }
    __syncthreads();                       // covers SZ writes AND HT staging

    // ---- res GEMM, K=64; weights direct from global (PROVEN r5-r10)
    const bf16x8* Wrg = (const bf16x8*)Wrp;
    f32x4 aR[8] = {};
#pragma unroll
    for (int kk = 0; kk < 2; ++kk) {
        int kgg = kk * 4 + quad;
        bf16x8 zs, wrf[8];
        zs = *(const bf16x8*)(SZ + (kgg * 64 + tq + lm) * 8);
#pragma unroll
        for (int i = 0; i < 8; ++i)
            wrf[i] = Wrg[kgg * 128 + i * 16 + lm];
#pragma unroll
        for (int i = 0; i < 8; ++i)
            aR[i] = MFMA(wrf[i], zs, aR[i]);
    }

    // ---- residual RMW in LDS (each lane owns its address -> race-free)
    const float scale = 0.70710678118654752f;
    {
        int tt = tq + lm;
#pragma unroll
        for (int i = 0; i < 8; ++i) {
            int co = i * 16 + quad * 4;
            short4 hv = *(const short4*)(HT + tt * 136 + co);
            short4 ho;
            ho.x = f2b((b2f(hv.x) + aR[i][0]) * scale);
            ho.y = f2b((b2f(hv.y) + aR[i][1]) * scale);
            ho.z = f2b((b2f(hv.z) + aR[i][2]) * scale);
            ho.w = f2b((b2f(hv.w) + aR[i][3]) * scale);
            *(short4*)(HT + tt * 136 + co) = ho;
        }
    }
    __syncthreads();

    // ---- coalesced h_out copy + z write
    short* hob = hout + (size_t)b * TLEN * CH;
    for (int u = tid; u < 1024; u += 256) {
        int tt = u >> 4, kg = u & 15;
        *(int4*)(hob + (size_t)(t0 + tt) * CH + kg * 8) = HT4[tt * 17 + kg];
    }
    short* zb = zlay + (size_t)b * TPRIME * ZK;
    for (int u = tid; u < 512; u += 256) {
        int tt = u >> 3, kg = u & 7;
        int ts = t0 + tt - LDIFF;
        if ((unsigned)ts < TPRIME)
            *(int4*)(zb + (size_t)ts * ZK + kg * 8) = *(const int4*)(SZ + (kg * 64 + tt) * 8);
    }
}

// ---------------------------------------------------------------- fused skip GEMM + relu -> sbf (PROVEN r9/r10)
__global__ __launch_bounds__(256) void k_skipgemm(
    const short* __restrict__ zbuf,   // [b][t'][1920]
    const short* __restrict__ Wsp,    // [kg240][co128][j8]
    short* __restrict__ sbf) {        // [b][t'][128]
    const int tid = threadIdx.x;
    const int l = tid & 63;
    const int w = tid >> 6;
    const int lm = l & 15;
    const int quad = l >> 4;
    const int b = blockIdx.y;
    const int t0 = blockIdx.x * 64;
    const int coq = (w & 1) * 64;
    const int tq = (w >> 1) * 32;
    const short* zb = zbuf + (size_t)b * TPRIME * ZK;
    const bf16x8* Wsg = (const bf16x8*)Wsp;

    f32x4 acc[4][2] = {};
    for (int kc = 0; kc < 60; ++kc) {
        bf16x8 af[4], bfr[2];
#pragma unroll
        for (int i = 0; i < 4; ++i)
            af[i] = Wsg[(kc * 4 + quad) * 128 + coq + i * 16 + lm];
#pragma unroll
        for (int j = 0; j < 2; ++j) {
            int tg = t0 + tq + j * 16 + lm;
            bf16x8 v = {};
            if (tg < TPRIME)
                v = *(const bf16x8*)(zb + (size_t)tg * ZK + kc * 32 + quad * 8);
            bfr[j] = v;
        }
#pragma unroll
        for (int i = 0; i < 4; ++i)
#pragma unroll
            for (int j = 0; j < 2; ++j)
                acc[i][j] = MFMA(af[i], bfr[j], acc[i][j]);
    }
    short* sb = sbf + (size_t)b * TPRIME * CH;
#pragma unroll
    for (int i = 0; i < 4; ++i)
#pragma unroll
        for (int j = 0; j < 2; ++j) {
            int tg = t0 + tq + j * 16 + lm;
            int co = coq + i * 16 + quad * 4;
            if (tg < TPRIME) {
                short4 v;
                v.x = f2b(fmaxf(acc[i][j][0], 0.f));
                v.y = f2b(fmaxf(acc[i][j][1], 0.f));
                v.z = f2b(fmaxf(acc[i][j][2], 0.f));
                v.w = f2b(fmaxf(acc[i][j][3], 0.f));
                *(short4*)(sb + (size_t)tg * CH + co) = v;
            }
        }
}

// ---------------------------------------------------------------- fused head (PROVEN r10, K-split x8)
__global__ __launch_bounds__(256) void k_head(
    const short* __restrict__ sbf,
    const short* __restrict__ Wp1,   // [16][3][4][4][128][8]
    const short* __restrict__ Wp2,   // [2][3][64][4][128][8]
    const float* __restrict__ Wlast,
    float* __restrict__ out) {
    __shared__ __align__(16) char smem[36448];   // SB1 18496 + Y 17952
    int4*  SB1 = (int4*)smem;                    // [68 rows][17 int4]
    short* Y   = (short*)(smem + 18496);         // [66 rows][136 shorts]
    __shared__ float red[64];
    const int tid = threadIdx.x;
    const int l = tid & 63;
    const int w = tid >> 6;
    const int lm = l & 15;
    const int quad = l >> 4;
    const int ks = blockIdx.y;                   // 8 splits x 2 cic
    const int b = blockIdx.z;
    const int t0 = blockIdx.x * 64;
    const short* sb = sbf + (size_t)b * TPRIME * CH;

    for (int u = tid; u < 1088; u += 256) {
        int tt = u >> 4, kg = u & 15;
        int tg = t0 - 2 + tt;
        int4 v = make_int4(0, 0, 0, 0);
        if ((unsigned)tg < TPRIME)
            v = *(const int4*)(sb + (size_t)tg * CH + kg * 8);
        SB1[tt * 17 + kg] = v;
    }
    if (tid < 64) red[tid] = 0.f;
    __syncthreads();

    const bf16x8* W1 = (const bf16x8*)Wp1;
    const bf16x8* W2 = (const bf16x8*)Wp2;
    const int cob2 = w >> 1;
    const int coq2 = (w & 1) * 64;
    f32x4 acc2[4][4] = {};

    for (int cic = ks * 2; cic < ks * 2 + 2; ++cic) {
        f32x4 acc1[2][5] = {};
#pragma unroll
        for (int tap = 0; tap < 3; ++tap)
#pragma unroll
            for (int kc = 0; kc < 4; ++kc) {
                bf16x8 a1[2], b1[5];
#pragma unroll
                for (int i = 0; i < 2; ++i)
                    a1[i] = W1[((size_t)(cic * 3 + tap) * 4 + kc) * 512 +
                               quad * 128 + 32 * w + i * 16 + lm];
#pragma unroll
                for (int j = 0; j < 5; ++j) {
                    int r = j * 16 + lm + tap;
                    b1[j] = *(const bf16x8*)(SB1 + r * 17 + kc * 4 + quad);
                }
#pragma unroll
                for (int i = 0; i < 2; ++i)
#pragma unroll
                    for (int j = 0; j < 5; ++j)
                        acc1[i][j] = MFMA(a1[i], b1[j], acc1[i][j]);
            }
        __syncthreads();
#pragma unroll
        for (int i = 0; i < 2; ++i)
#pragma unroll
            for (int j = 0; j < 5; ++j) {
                int row = j * 16 + lm;
                if (row < 66) {
                    int co = 32 * w + i * 16 + quad * 4;
                    const bool valid = (unsigned)(t0 - 1 + row) < TPRIME;  // zero-pad edges
                    short4 v;
                    v.x = valid ? f2b(fmaxf(acc1[i][j][0], 0.f)) : (short)0;
                    v.y = valid ? f2b(fmaxf(acc1[i][j][1], 0.f)) : (short)0;
                    v.z = valid ? f2b(fmaxf(acc1[i][j][2], 0.f)) : (short)0;
                    v.w = valid ? f2b(fmaxf(acc1[i][j][3], 0.f)) : (short)0;
                    *(short4*)(Y + row * 136 + co) = v;
                }
            }
        __syncthreads();
#pragma unroll
        for (int tap = 0; tap < 3; ++tap)
#pragma unroll
            for (int kc = 0; kc < 4; ++kc) {
                bf16x8 a2[4], b2[4];
#pragma unroll
                for (int i = 0; i < 4; ++i)
                    a2[i] = W2[((size_t)(cob2 * 3 + tap) * 64 + cic * 4 + kc) * 512 +
                               quad * 128 + coq2 + i * 16 + lm];
#pragma unroll
                for (int j = 0; j < 4; ++j) {
                    int row = j * 16 + lm + tap;
                    b2[j] = *(const bf16x8*)(Y + row * 136 + kc * 32 + quad * 8);
                }
#pragma unroll
                for (int i = 0; i < 4; ++i)
#pragma unroll
                    for (int j = 0; j < 4; ++j)
                        acc2[i][j] = MFMA(a2[i], b2[j], acc2[i][j]);
            }
    }

    float4 wv[4];
#pragma unroll
    for (int i = 0; i < 4; ++i)
        wv[i] = *(const float4*)(Wlast + cob2 * 128 + coq2 + i * 16 + quad * 4);
#pragma unroll
    for (int j = 0; j < 4; ++j) {
        float s = 0.f;
#pragma unroll
        for (int i = 0; i < 4; ++i)
            s += wv[i].x * acc2[i][j][0] + wv[i].y * acc2[i][j][1] +
                 wv[i].z * acc2[i][j][2] + wv[i].w * acc2[i][j][3];
        atomicAdd(&red[j * 16 + lm], s);
    }
    __syncthreads();
    if (tid < 64) {
        int tg = t0 + tid;
        if (tg < TPRIME) atomicAdd(&out[(size_t)b * TPRIME + tg], red[tid]);
    }
}

// ---------------------------------------------------------------- bias init (PROVEN r4)
__global__ void k_bias(float* __restrict__ out, const float* __restrict__ bl) {
    int i = blockIdx.x * 256 + threadIdx.x;
    if (i < BATCH * TPRIME) out[i] = bl[0];
}

extern "C" void kernel_launch(void* const* d_in, const int* in_sizes, int n_in,
                              void* d_out, int out_size, void* d_ws, size_t ws_size,
                              hipStream_t stream) {
    const float* x = (const float*)d_in[0];
    const float* Wf = (const float*)d_in[1];
    const float* Wdil = (const float*)d_in[2];
    const float* Wskip = (const float*)d_in[3];
    const float* Wres = (const float*)d_in[4];
    const float* Wfc1 = (const float*)d_in[5];
    const float* Wfc2 = (const float*)d_in[6];
    const float* Wlast = (const float*)d_in[7];
    const float* blast = (const float*)d_in[8];
    float* out = (float*)d_out;

    char* p = (char*)d_ws;
    auto alloc = [&](size_t bytes) { char* r = p; p += (bytes + 255) & ~(size_t)255; return r; };
    short* zbuf  = (short*)alloc((size_t)BATCH * TPRIME * ZK * 2);   // 157.4 MB
    short* WpD   = (short*)alloc((size_t)NLAYERS * 49152 * 2);       // 2.95 MB
    short* Wsp   = (short*)alloc((size_t)NLAYERS * 8192 * 2);        // 0.49 MB (K-major image)
    short* Wrp   = (short*)alloc((size_t)NLAYERS * 8192 * 2);        // 0.49 MB
    short* Wp1   = (short*)alloc((size_t)786432 * 2);                // 1.5 MB
    short* Wp2   = (short*)alloc((size_t)1572864 * 2);               // 3.0 MB
    short* hA    = (short*)alloc((size_t)BATCH * TLEN * CH * 2);     // 16.78 MB
    short* hB    = (short*)alloc((size_t)BATCH * TLEN * CH * 2);     // 16.78 MB
    short* sbf   = (short*)alloc((size_t)BATCH * TPRIME * CH * 2);   // 10.49 MB
    // total ~210 MB

    k_prep_conv<<<5760, 256, 0, stream>>>(Wdil, WpD, 128, 4, 1474560);
    k_prep_conv<<<3072, 256, 0, stream>>>(Wfc1, Wp1, 128, 4, 786432);
    k_prep_conv<<<6144, 256, 0, stream>>>(Wfc2, Wp2, 2048, 64, 1572864);
    k_prep_sr<<<960, 256, 0, stream>>>(Wskip, Wres, Wsp, Wrp);
    k_first<<<8192, 256, 0, stream>>>(x, Wf, hA);

    short* hin = hA;
    short* hout = hB;
    for (int lyr = 0; lyr < NLAYERS; ++lyr) {
        int d = 1 << (lyr % 10);
        k_layer<<<dim3(TLEN / 64, BATCH), 256, 0, stream>>>(
            hin, hout, zbuf + (size_t)lyr * 64,
            WpD + (size_t)lyr * 49152, Wrp + (size_t)lyr * 8192, d);
        short* tmp = hin; hin = hout; hout = tmp;
    }

    k_skipgemm<<<dim3(161, BATCH), 256, 0, stream>>>(zbuf, Wsp, sbf);
    k_bias<<<161, 256, 0, stream>>>(out, blast);
    k_head<<<dim3(161, 8, BATCH), 256, 0, stream>>>(sbf, Wp1, Wp2, Wlast, out);
}